// Round 4
// baseline (165.101 us; speedup 1.0000x reference)
//
#include <hip/hip_runtime.h>

typedef __attribute__((ext_vector_type(8))) short bf16x8;
typedef __attribute__((ext_vector_type(4))) float f32x4;

__device__ __forceinline__ float bf2f(unsigned short u) {
  return __uint_as_float(((unsigned int)u) << 16);
}
__device__ __forceinline__ unsigned short f2bf(float f) {
  unsigned int u = __float_as_uint(f);
  u += 0x7fffu + ((u >> 16) & 1u);
  return (unsigned short)(u >> 16);
}

// ---------------- workspace layout (bytes) ----------------
constexpr size_t OFF_XPAD = 0;
constexpr size_t SZ_XPAD  = (size_t)8 * 66 * 66 * 128 * 2;        // 8,921,088
constexpr size_t OFF_WB   = OFF_XPAD + SZ_XPAD;
constexpr size_t SZ_WB    = (size_t)9 * 16 * 256 * 8 * 2;         // 589,824
constexpr size_t OFF_WS2  = OFF_WB + SZ_WB;
constexpr size_t SZ_WS2   = (size_t)16 * 256 * 8 * 2;             // 65,536
constexpr size_t OFF_WO   = OFF_WS2 + SZ_WS2;
constexpr size_t SZ_WO    = (size_t)9 * 16 * 32 * 8 * 2;          // 73,728
// y_main bf16 TRANSPOSED [256][32768]
constexpr size_t OFF_YM   = OFF_WO + SZ_WO;
constexpr size_t SZ_YM    = (size_t)256 * 32768 * 2;              // 16,777,216
constexpr size_t OFF_PART = OFF_YM + SZ_YM;
constexpr size_t SZ_PART  = (size_t)1024 * 256 * 2 * 4;           // 2,097,152
constexpr size_t OFF_STAT = OFF_PART + SZ_PART;

// ---------------- x: NCHW fp32 -> NHWC bf16 zero-padded ----------------
__global__ __launch_bounds__(256) void k_prep_x(const float* __restrict__ x,
                                                unsigned short* __restrict__ xp) {
  int blk = blockIdx.x;               // 1024 = (b*64 + h)*2 + chalf
  int b = blk >> 7, h = (blk >> 1) & 63, chalf = blk & 1;
  int t = threadIdx.x;
  __shared__ float tile[16][66];
  for (int cc = 0; cc < 4; ++cc) {
    int c0 = (chalf * 4 + cc) * 16;
    int wr = t & 63, cl = t >> 6;
#pragma unroll
    for (int i = 0; i < 4; ++i) {
      int c = c0 + cl * 4 + i;
      tile[cl * 4 + i][wr] = x[(((size_t)b * 128 + c) * 64 + h) * 64 + wr];
    }
    __syncthreads();
    int ww = t >> 2, cq = t & 3;
    ushort4 u4;
    u4.x = f2bf(tile[cq * 4 + 0][ww]);
    u4.y = f2bf(tile[cq * 4 + 1][ww]);
    u4.z = f2bf(tile[cq * 4 + 2][ww]);
    u4.w = f2bf(tile[cq * 4 + 3][ww]);
    *(ushort4*)(xp + ((size_t)(b * 66 + h + 1) * 66 + (ww + 1)) * 128 + c0 + cq * 4) = u4;
    __syncthreads();
  }
}

// ---------------- weight packing ----------------
__global__ __launch_bounds__(256) void k_pack_w(const float* __restrict__ wdef,
                                                const float* __restrict__ wsc,
                                                const float* __restrict__ woff,
                                                unsigned short* __restrict__ wB,
                                                unsigned short* __restrict__ wS,
                                                unsigned short* __restrict__ wO) {
  int tid = blockIdx.x * 256 + threadIdx.x;
  if (tid < 294912) {
    int k8 = tid & 7, n = (tid >> 3) & 255, kb = (tid >> 11) & 15, tap = tid >> 15;
    int c = kb * 8 + k8;
    wB[tid] = f2bf(wdef[((size_t)n * 128 + c) * 9 + tap]);
  } else if (tid < 294912 + 32768) {
    int i = tid - 294912;
    int k8 = i & 7, n = (i >> 3) & 255, kb = i >> 11;
    wS[i] = f2bf(wsc[(size_t)n * 128 + kb * 8 + k8]);
  } else if (tid < 294912 + 32768 + 36864) {
    int i = tid - 327680;
    int k8 = i & 7, n = (i >> 3) & 31, kb = (i >> 8) & 15, tap = i >> 12;
    int c = kb * 8 + k8;
    wO[i] = f2bf(n < 18 ? woff[((size_t)n * 128 + c) * 9 + tap] : 0.f);
  }
}

// ---------------- main: offset conv + deform-sample + 3x3 conv GEMM + BN partials ----------------
// 1024 blocks x 256 thr (4 waves); 32-px half-row tile; double-buffered LDS.
__global__ __launch_bounds__(256, 4) void k_main(const unsigned short* __restrict__ xp,
                                                 const unsigned short* __restrict__ wB,
                                                 const unsigned short* __restrict__ wO,
                                                 const float* __restrict__ boff,
                                                 const float* __restrict__ bdef,
                                                 unsigned short* __restrict__ ymain,
                                                 float* __restrict__ partials) {
  int blk = blockIdx.x;               // (b*64 + h)*2 + half
  int b = blk >> 7, h = (blk >> 1) & 63, half = blk & 1;
  int px0 = half * 32;
  int t = threadIdx.x;
  int lane = t & 63, wid = t >> 6;    // 4 waves
  int m = lane & 15, quad = lane >> 4;
  __shared__ __align__(16) unsigned short At[2][32 * 136];  // 2 x 8704 B
  __shared__ float offsL[9][32][2];                          // 2304 B

  // ---- phase 0: inline offset conv (this tile's 18 offsets -> LDS), waves 0-1 ----
  if (wid < 2) {
    f32x4 a0 = {0.f, 0.f, 0.f, 0.f}, a1 = {0.f, 0.f, 0.f, 0.f};
    int px = wid * 16 + m;
    const unsigned short* xbase = xp + ((size_t)(b * 66 + h) * 66 + px0 + px) * 128 + quad * 8;
    for (int tap = 0; tap < 9; ++tap) {
      const unsigned short* arow = xbase + ((tap / 3) * 66 + (tap % 3)) * 128;
#pragma unroll
      for (int kk = 0; kk < 4; ++kk) {
        bf16x8 a = *(const bf16x8*)(arow + kk * 32);
        const unsigned short* bb = wO + (size_t)(tap * 16 + kk * 4 + quad) * 256;
        bf16x8 b0 = *(const bf16x8*)(bb + m * 8);
        bf16x8 b1 = *(const bf16x8*)(bb + (16 + m) * 8);
        a0 = __builtin_amdgcn_mfma_f32_16x16x32_bf16(a, b0, a0, 0, 0, 0);
        a1 = __builtin_amdgcn_mfma_f32_16x16x32_bf16(a, b1, a1, 0, 0, 0);
      }
    }
#pragma unroll
    for (int r = 0; r < 4; ++r) {
      int pxs = wid * 16 + quad * 4 + r;
      offsL[m >> 1][pxs][m & 1] = a0[r] + boff[m];   // n=m in [0,16): tap=n>>1, comp=n&1
      if (m < 2) offsL[8][pxs][m] = a1[r] + boff[16 + m];
    }
  }
  __syncthreads();

  f32x4 acc[2][4];
#pragma unroll
  for (int i = 0; i < 2; ++i)
#pragma unroll
    for (int j = 0; j < 4; ++j) acc[i][j] = (f32x4){0.f, 0.f, 0.f, 0.f};

  // sampling role: thread = px_s*8 + sub; 8 consecutive lanes cover 128B contiguous
  int px_s = t >> 3, sub = t & 7;
  const unsigned short* xb_base = xp + (size_t)b * 66 * 66 * 128;
  int nb = wid * 64;                  // mfma role: N range per wave, M=32 shared

  auto sample_prep = [&](int tap, float* wgt, const unsigned short** p) {
    float2 ov = *(const float2*)&offsL[tap][px_s][0];
    int ky = tap / 3 - 1, kx = tap % 3 - 1;
    float py = (float)(h + ky) + ov.x;
    float pxf = (float)(px0 + px_s + kx) + ov.y;
    float y0f = floorf(py), x0f = floorf(pxf);
    float fy = py - y0f, fx = pxf - x0f;
    int iy0 = (int)y0f, ix0 = (int)x0f;
#pragma unroll
    for (int j = 0; j < 4; ++j) {
      int iy = iy0 + (j >> 1), ix = ix0 + (j & 1);
      float wy = (j >> 1) ? fy : 1.f - fy;
      float wx = (j & 1) ? fx : 1.f - fx;
      bool valid = (iy >= 0) && (iy < 64) && (ix >= 0) && (ix < 64);
      int iyc = min(max(iy, 0), 63), ixc = min(max(ix, 0), 63);
      wgt[j] = valid ? wy * wx : 0.f;
      p[j] = xb_base + ((size_t)(iyc + 1) * 66 + (ixc + 1)) * 128 + sub * 8;
    }
  };
  // gathers: ch = sub*8 + g*64, g in {0,1}
  auto load_all = [&](const unsigned short** p, bf16x8 (*v)[4]) {
#pragma unroll
    for (int g = 0; g < 2; ++g)
#pragma unroll
      for (int j = 0; j < 4; ++j)
        v[g][j] = *(const bf16x8*)(p[j] + g * 64);
  };
  auto store_all = [&](unsigned short* dst, const float* wgt, bf16x8 (*v)[4]) {
#pragma unroll
    for (int g = 0; g < 2; ++g) {
      bf16x8 o;
#pragma unroll
      for (int j = 0; j < 8; ++j) {
        float s = fmaf(wgt[0], bf2f((unsigned short)v[g][0][j]),
                  fmaf(wgt[1], bf2f((unsigned short)v[g][1][j]),
                  fmaf(wgt[2], bf2f((unsigned short)v[g][2][j]),
                       wgt[3] * bf2f((unsigned short)v[g][3][j]))));
        o[j] = (short)f2bf(s);
      }
      *(bf16x8*)(dst + g * 64) = o;
    }
  };
  auto mfma_tap = [&](const unsigned short* buf, int tap) {
#pragma unroll
    for (int kk = 0; kk < 4; ++kk) {
      bf16x8 af[2];
#pragma unroll
      for (int ms = 0; ms < 2; ++ms)
        af[ms] = *(const bf16x8*)(buf + (ms * 16 + m) * 136 + kk * 32 + quad * 8);
#pragma unroll
      for (int ns = 0; ns < 4; ++ns) {
        bf16x8 bfr = *(const bf16x8*)(wB + ((size_t)(tap * 16 + kk * 4 + quad) * 256 + nb + ns * 16 + m) * 8);
#pragma unroll
        for (int ms = 0; ms < 2; ++ms)
          acc[ms][ns] = __builtin_amdgcn_mfma_f32_16x16x32_bf16(af[ms], bfr, acc[ms][ns], 0, 0, 0);
      }
    }
  };

  // prologue: sample tap 0 into buf 0
  {
    float wgt[4]; const unsigned short* p[4]; bf16x8 v[2][4];
    sample_prep(0, wgt, p);
    load_all(p, v);
    store_all(&At[0][px_s * 136 + sub * 8], wgt, v);
  }
#pragma unroll
  for (int tap = 0; tap < 9; ++tap) {
    __syncthreads();
    const unsigned short* cur = At[tap & 1];
    if (tap < 8) {
      float wgt[4]; const unsigned short* p[4]; bf16x8 v[2][4];
      sample_prep(tap + 1, wgt, p);
      load_all(p, v);               // 8 gathers in flight...
      mfma_tap(cur, tap);           // ...hidden behind 32 MFMAs
      store_all(&At[(tap + 1) & 1][px_s * 136 + sub * 8], wgt, v);
    } else {
      mfma_tap(cur, tap);
    }
  }

  // ---- epilogue: bias + BN partials; LDS transpose -> ymain [n][pix] ----
  __syncthreads();                    // all waves done reading At
  unsigned short* yb = &At[0][0];     // 32 x 258 bf16 (16512 B)
#pragma unroll
  for (int ns = 0; ns < 4; ++ns) {
    int n = nb + ns * 16 + m;
    float bias = bdef[n];
    float s = 0.f, q = 0.f;
#pragma unroll
    for (int ms = 0; ms < 2; ++ms) {
#pragma unroll
      for (int r = 0; r < 4; ++r) {
        int px = ms * 16 + quad * 4 + r;
        float v = acc[ms][ns][r] + bias;
        yb[px * 258 + n] = f2bf(v);
        s += v;
        q += v * v;
      }
    }
    s += __shfl_xor(s, 16); s += __shfl_xor(s, 32);
    q += __shfl_xor(q, 16); q += __shfl_xor(q, 32);
    if (quad == 0) {
      partials[((size_t)blk * 256 + n) * 2 + 0] = s;
      partials[((size_t)blk * 256 + n) * 2 + 1] = q;
    }
  }
  __syncthreads();
  {
    int px_l = t & 31, n_g = t >> 5;  // 8 groups x 32 n
    const unsigned short* col = yb + px_l * 258;
    unsigned short* gdst = ymain + blk * 32 + px_l;
#pragma unroll
    for (int i = 0; i < 32; ++i) {
      int n = n_g * 32 + i;
      gdst[(size_t)n * 32768] = col[n];   // lanes px_l consecutive -> 64B lines
    }
  }
}

// ---------------- BN stats reduce ----------------
__global__ __launch_bounds__(64) void k_stats(const float* __restrict__ partials,
                                              const float* __restrict__ gamma,
                                              const float* __restrict__ beta,
                                              float* __restrict__ stats) {
  int ch = blockIdx.x;                // 256
  int L = threadIdx.x;                // 64
  float s = 0.f, q = 0.f;
#pragma unroll
  for (int i = 0; i < 16; ++i) {
    int row = i * 64 + L;
    s += partials[((size_t)row * 256 + ch) * 2 + 0];
    q += partials[((size_t)row * 256 + ch) * 2 + 1];
  }
#pragma unroll
  for (int d = 1; d < 64; d <<= 1) { s += __shfl_xor(s, d); q += __shfl_xor(q, d); }
  if (L == 0) {
    float mean = s * (1.f / 32768.f);
    float var = q * (1.f / 32768.f) - mean * mean;
    float inv = rsqrtf(var + 1e-5f);
    float A = gamma[ch] * inv;
    stats[ch * 2 + 0] = A;
    stats[ch * 2 + 1] = beta[ch] - mean * A;
  }
}

// ---------------- final: 1x1 shortcut MFMA + BN apply + ReLU, direct NCHW store ----------------
// D rows = ch (A=weights), cols = px (B=x) -> coalesced out stores; no LDS, no barriers.
__global__ __launch_bounds__(256, 4) void k_final(const unsigned short* __restrict__ xp,
                                                  const unsigned short* __restrict__ wS,
                                                  const unsigned short* __restrict__ ymain,
                                                  const float* __restrict__ stats,
                                                  const float* __restrict__ bsc,
                                                  float* __restrict__ out) {
  int blk = blockIdx.x;               // (b*64 + h)*2 + half
  int b = blk >> 7, h = (blk >> 1) & 63, half = blk & 1;
  int t = threadIdx.x;
  int lane = t & 63, wid = t >> 6;
  int m = lane & 15, quad = lane >> 4;
  f32x4 acc[4][2];                    // [ch tile][px tile]
#pragma unroll
  for (int i = 0; i < 4; ++i)
#pragma unroll
    for (int j = 0; j < 2; ++j) acc[i][j] = (f32x4){0.f, 0.f, 0.f, 0.f};
  const unsigned short* xrow = xp + ((size_t)(b * 66 + h + 1) * 66 + 1 + half * 32) * 128;
  int nb = wid * 64;
#pragma unroll
  for (int kk = 0; kk < 4; ++kk) {
    bf16x8 xf[2];
#pragma unroll
    for (int pt = 0; pt < 2; ++pt)
      xf[pt] = *(const bf16x8*)(xrow + (pt * 16 + m) * 128 + kk * 32 + quad * 8);
#pragma unroll
    for (int ct = 0; ct < 4; ++ct) {
      bf16x8 wf = *(const bf16x8*)(wS + ((size_t)(kk * 4 + quad) * 256 + nb + ct * 16 + m) * 8);
#pragma unroll
      for (int pt = 0; pt < 2; ++pt)
        acc[ct][pt] = __builtin_amdgcn_mfma_f32_16x16x32_bf16(wf, xf[pt], acc[ct][pt], 0, 0, 0);
    }
  }
#pragma unroll
  for (int ct = 0; ct < 4; ++ct) {
#pragma unroll
    for (int r = 0; r < 4; ++r) {
      int ch = nb + ct * 16 + quad * 4 + r;
      float A = stats[ch * 2], Bc = stats[ch * 2 + 1];
      float bs = bsc[ch] + Bc;
#pragma unroll
      for (int pt = 0; pt < 2; ++pt) {
        int px = pt * 16 + m;
        float ym = bf2f(ymain[(size_t)ch * 32768 + blk * 32 + px]);
        float v = fmaxf(fmaf(ym, A, bs) + acc[ct][pt][r], 0.f);
        out[(((size_t)(b * 256 + ch) * 64 + h) * 64) + half * 32 + px] = v;
      }
    }
  }
}

extern "C" void kernel_launch(void* const* d_in, const int* in_sizes, int n_in,
                              void* d_out, int out_size, void* d_ws, size_t ws_size,
                              hipStream_t stream) {
  const float* x     = (const float*)d_in[0];
  const float* w_off = (const float*)d_in[1];
  const float* b_off = (const float*)d_in[2];
  const float* w_def = (const float*)d_in[3];
  const float* b_def = (const float*)d_in[4];
  const float* gamma = (const float*)d_in[5];
  const float* beta  = (const float*)d_in[6];
  const float* w_sc  = (const float*)d_in[7];
  const float* b_sc  = (const float*)d_in[8];
  float* out = (float*)d_out;

  char* ws = (char*)d_ws;
  unsigned short* xpad  = (unsigned short*)(ws + OFF_XPAD);
  unsigned short* wB    = (unsigned short*)(ws + OFF_WB);
  unsigned short* wS    = (unsigned short*)(ws + OFF_WS2);
  unsigned short* wO    = (unsigned short*)(ws + OFF_WO);
  unsigned short* ymain = (unsigned short*)(ws + OFF_YM);
  float* partials       = (float*)(ws + OFF_PART);
  float* stats          = (float*)(ws + OFF_STAT);

  hipMemsetAsync(xpad, 0, SZ_XPAD, stream);
  k_prep_x<<<1024, 256, 0, stream>>>(x, xpad);
  k_pack_w<<<1424, 256, 0, stream>>>(w_def, w_sc, w_off, wB, wS, wO);
  k_main<<<1024, 256, 0, stream>>>(xpad, wB, wO, b_off, b_def, ymain, partials);
  k_stats<<<256, 64, 0, stream>>>(partials, gamma, beta, stats);
  k_final<<<1024, 256, 0, stream>>>(xpad, wS, ymain, stats, b_sc, out);
}